// Round 5
// baseline (179.998 us; speedup 1.0000x reference)
//
#include <hip/hip_runtime.h>

typedef __attribute__((ext_vector_type(8))) _Float16 f16x8;
typedef __attribute__((ext_vector_type(4))) float   f32x4;

namespace {
constexpr int kB    = 8192;
constexpr int kTH   = 11;
constexpr int kTP   = 80;
constexpr int kM    = 16;    // batch rows per block (MFMA M)
constexpr int kStrH = 72;    // H-plane row stride in fp16 units (144 B: 16B-aligned)
}

// 8 fp32 -> fp16x8 (round-to-nearest)
__device__ __forceinline__ f16x8 cvt8(const float* f) {
    f16x8 v;
#pragma unroll
    for (int j = 0; j < 8; ++j) v[j] = (_Float16)f[j];
    return v;
}

// B-fragment (single fp16) for column `col`: B[k][col] = W[col][k].
__device__ __forceinline__ void loadB1(const float* __restrict__ W, int col, int q,
                                       f16x8 (&Bf)[2]) {
#pragma unroll
    for (int c = 0; c < 2; ++c) {
        const float* src = W + col * 64 + c * 32 + q * 8;
        const float4 a = reinterpret_cast<const float4*>(src)[0];
        const float4 b = reinterpret_cast<const float4*>(src)[1];
        float f[8] = {a.x, a.y, a.z, a.w, b.x, b.y, b.z, b.w};
        Bf[c] = cvt8(f);
    }
}

// fc B-fragment: only cols p<2 are real (fcW is 2x64); others zero.
__device__ __forceinline__ void loadBfc(const float* __restrict__ fcW, int p, int q,
                                        f16x8 (&Bf)[2]) {
#pragma unroll
    for (int c = 0; c < 2; ++c) {
        float f[8];
#pragma unroll
        for (int j = 0; j < 8; ++j)
            f[j] = (p < 2) ? fcW[p * 64 + c * 32 + q * 8 + j] : 0.f;
        Bf[c] = cvt8(f);
    }
}

// G = w0 (x) fcW[0] + w1 (x) fcW[1]  (rank-2 folded feedback matrix)
__device__ __forceinline__ void loadBG(const float* __restrict__ fcW, float w0, float w1,
                                       int q, f16x8 (&Bf)[2]) {
#pragma unroll
    for (int c = 0; c < 2; ++c) {
        float f[8];
#pragma unroll
        for (int j = 0; j < 8; ++j) {
            const int k = c * 32 + q * 8 + j;
            f[j] = w0 * fcW[k] + w1 * fcW[64 + k];
        }
        Bf[c] = cvt8(f);
    }
}

__device__ __forceinline__ f16x8 read_frag(const _Float16* plane, int off) {
    return *reinterpret_cast<const f16x8*>(plane + off);
}

// single-term accumulate: D += A*B (A = fp16 h, B = fp16 W)
__device__ __forceinline__ f32x4 mfma1(f16x8 a, f16x8 b, f32x4 acc) {
    return __builtin_amdgcn_mfma_f32_16x16x32_f16(a, b, acc, 0, 0, 0);
}

// tanh via raw v_exp/v_rcp: 1 - 2*rcp(2^(2*log2e*x)+1); saturates safely.
__device__ __forceinline__ float fast_tanh(float x) {
    const float e = __builtin_amdgcn_exp2f(x * 2.8853900817779268f);  // 2/ln2
    return fmaf(-2.0f, __builtin_amdgcn_rcpf(e + 1.0f), 1.0f);
}

// drain own LDS writes, then publish step counter (lane 0 only)
__device__ __forceinline__ void publish(volatile int* f, int wv, int lane, int sv) {
    asm volatile("s_waitcnt lgkmcnt(0)" ::: "memory");
    if (lane == 0) f[wv] = sv;
}

// spin until all 4 waves' counters >= target (bounded for hang safety)
__device__ __forceinline__ void spin_ge(const volatile int* f, int target) {
    int guard = 0;
    while (true) {
        asm volatile("" ::: "memory");
        const int m = min(min(f[0], f[1]), min(f[2], f[3]));
        if (m >= target) break;
        if (++guard > (1 << 22)) break;   // safety escape; never hit if protocol holds
    }
    asm volatile("" ::: "memory");        // fence: data reads stay below the spin
}

// R14 = R9 work assignment (512 blocks x 4 col-split waves, 2 blocks/CU)
// with s_barrier REPLACED by elastic producer-flag sync + ping-pong H planes.
// No global convergence, no release broadcast, no vmcnt drain: each wave reads
// the instant min(prod flags) covers its step. 2-slot reuse is safe because
// producing step s-1 requires having consumed step s-2 (register data dep).
__global__ __attribute__((amdgpu_waves_per_eu(2, 2))) __launch_bounds__(256)
void traj_rnn_kernel(
    const float* __restrict__ x,
    const float* __restrict__ eWih0, const float* __restrict__ eWhh0,
    const float* __restrict__ ebih0, const float* __restrict__ ebhh0,
    const float* __restrict__ eWih1, const float* __restrict__ eWhh1,
    const float* __restrict__ ebih1, const float* __restrict__ ebhh1,
    const float* __restrict__ dWih0, const float* __restrict__ dWhh0,
    const float* __restrict__ dbih0, const float* __restrict__ dbhh0,
    const float* __restrict__ dWih1, const float* __restrict__ dWhh1,
    const float* __restrict__ dbih1, const float* __restrict__ dbhh1,
    const float* __restrict__ fcW, const float* __restrict__ fcb,
    float* __restrict__ out)
{
    const int tid  = threadIdx.x;
    const int wv   = tid >> 6;          // n-tile owned by this wave (0..3)
    const int lane = tid & 63;
    const int p    = lane & 15;         // A-m / C-col-within-tile
    const int q    = lane >> 4;         // k-quad / C row-quad
    const int col  = wv * 16 + p;       // this lane's hidden-unit column
    const int r0   = blockIdx.x * kM;

    __shared__ __align__(16) _Float16 H1s[2][kM * kStrH];   // ping-pong by step&1
    __shared__ __align__(16) _Float16 H2s[2][kM * kStrH];
    __shared__ __align__(16) float xbuf[kM * kTH * 2];
    __shared__ __align__(16) float predbuf[kM * kTP * 2];
    __shared__ __align__(16) int p1f[4];   // per-wave h1 producer step
    __shared__ __align__(16) int p2f[4];   // per-wave h2 producer step

    for (int i = tid; i < kM * kTH * 2; i += 256)
        xbuf[i] = x[r0 * (kTH * 2) + i];
    if (tid < 4) { p1f[tid] = 0; p2f[tid] = 0; }

    f16x8 H1f[2], H2f[2];
#pragma unroll
    for (int c = 0; c < 2; ++c) {
        H1f[c] = f16x8{0, 0, 0, 0, 0, 0, 0, 0};
        H2f[c] = f16x8{0, 0, 0, 0, 0, 0, 0, 0};
    }
    __syncthreads();   // xbuf + flag init visible (only hard barrier until flush)

    const int aoff = p * kStrH;  // A-fragment base for this lane's m-row

    // ================= encoder: 11 steps (sv = 1..11) =================
    {
        const float b0 = ebih0[col] + ebhh0[col];
        const float b1 = ebih1[col] + ebhh1[col];
        const float w0 = eWih0[col * 2 + 0];
        const float w1 = eWih0[col * 2 + 1];
        f16x8 B0[2], B1[2], B2[2];
        loadB1(eWhh0, col, q, B0);   // Whh0
        loadB1(eWih1, col, q, B1);   // Wih1
        loadB1(eWhh1, col, q, B2);   // Whh1

        f32x4 P1 = {b0, b0, b0, b0};       // b0 + Whh0 . h1 (h1 = 0 initially)

#pragma unroll 1
        for (int t = 0; t < kTH; ++t) {
            const int sv = t + 1;
            _Float16* h1p = H1s[sv & 1];
            _Float16* h2p = H2s[sv & 1];
            // h1 = tanh(P1 + x-term), write to slot
#pragma unroll
            for (int r = 0; r < 4; ++r) {
                const float2 xv = *reinterpret_cast<const float2*>(
                    &xbuf[(4 * q + r) * (kTH * 2) + 2 * t]);
                const float h1 = fast_tanh(fmaf(w0, xv.x, fmaf(w1, xv.y, P1[r])));
                h1p[(4 * q + r) * kStrH + col] = (_Float16)h1;
            }
            publish(p1f, wv, lane, sv);
            // filler: layer-2 partial on OLD H2 while others finish writing
            f32x4 a2 = {b1, b1, b1, b1};
            a2 = mfma1(H2f[0], B2[0], a2);
            a2 = mfma1(H2f[1], B2[1], a2);
            spin_ge(p1f, sv);

            H1f[0] = read_frag(h1p, aoff + q * 8);
            H1f[1] = read_frag(h1p, aoff + 32 + q * 8);
            a2 = mfma1(H1f[0], B1[0], a2);
            a2 = mfma1(H1f[1], B1[1], a2);
#pragma unroll
            for (int r = 0; r < 4; ++r) {
                const float h2 = fast_tanh(a2[r]);
                h2p[(4 * q + r) * kStrH + col] = (_Float16)h2;
            }
            publish(p2f, wv, lane, sv);
            // filler: next-P1 recurrent term (H1 frags live)
            f32x4 np = {b0, b0, b0, b0};
            np = mfma1(H1f[0], B0[0], np);
            np = mfma1(H1f[1], B0[1], np);
            spin_ge(p2f, sv);

            H2f[0] = read_frag(h2p, aoff + q * 8);
            H2f[1] = read_frag(h2p, aoff + 32 + q * 8);
            P1 = np;
        }
    }

    // ================= decoder: 80 autoregressive steps (sv = 12..91) ==========
    {
        const float b0 = dbih0[col] + dbhh0[col];
        const float b1 = dbih1[col] + dbhh1[col];
        const float w0 = dWih0[col * 2 + 0];
        const float w1 = dWih0[col * 2 + 1];
        const float fb0 = fcb[0];
        const float fb1 = fcb[1];
        // folded bias: feedback constant term absorbed into layer-1 bias
        const float b0p = b0 + w0 * fb0 + w1 * fb1;
        const float fbp = (p == 0) ? fb0 : fb1;   // for LDS stash from p<2 lanes
        f16x8 B0[2], B1[2], B2[2], BF[2], BG[2];
        loadB1(dWhh0, col, q, B0);
        loadB1(dWih1, col, q, B1);
        loadB1(dWhh1, col, q, B2);
        loadBfc(fcW, p, q, BF);
        loadBG(fcW, w0, w1, q, BG);   // rank-2 folded feedback matrix

        // P1 for the FIRST decoder step: b0 + Whh0.h1_enc + w0*x_last0 + w1*x_last1
        f32x4 P1 = {b0, b0, b0, b0};
        P1 = mfma1(H1f[0], B0[0], P1);
        P1 = mfma1(H1f[1], B0[1], P1);
#pragma unroll
        for (int r = 0; r < 4; ++r) {
            const float2 xv = *reinterpret_cast<const float2*>(
                &xbuf[(4 * q + r) * (kTH * 2) + 2 * (kTH - 1)]);
            P1[r] = fmaf(w0, xv.x, fmaf(w1, xv.y, P1[r]));
        }

#pragma unroll 2
        for (int t = 0; t < kTP; ++t) {
            const int sv = kTH + 1 + t;
            _Float16* h1p = H1s[sv & 1];
            _Float16* h2p = H2s[sv & 1];
            // h1 = tanh(P1) (P1 complete incl. folded feedback), write to slot
#pragma unroll
            for (int r = 0; r < 4; ++r) {
                const float h1 = fast_tanh(P1[r]);
                h1p[(4 * q + r) * kStrH + col] = (_Float16)h1;
            }
            publish(p1f, wv, lane, sv);
            // filler: layer-2 partial on OLD H2
            f32x4 a2 = {b1, b1, b1, b1};
            a2 = mfma1(H2f[0], B2[0], a2);
            a2 = mfma1(H2f[1], B2[1], a2);
            spin_ge(p1f, sv);

            H1f[0] = read_frag(h1p, aoff + q * 8);
            H1f[1] = read_frag(h1p, aoff + 32 + q * 8);
            a2 = mfma1(H1f[0], B1[0], a2);
            a2 = mfma1(H1f[1], B1[1], a2);
#pragma unroll
            for (int r = 0; r < 4; ++r) {
                const float h2 = fast_tanh(a2[r]);
                h2p[(4 * q + r) * kStrH + col] = (_Float16)h2;
            }
            publish(p2f, wv, lane, sv);
            // filler: nb = B0.h1 (operand live in registers)
            f32x4 nb = {0.f, 0.f, 0.f, 0.f};
            nb = mfma1(H1f[0], B0[0], nb);
            nb = mfma1(H1f[1], B0[1], nb);
            spin_ge(p2f, sv);

            H2f[0] = read_frag(h2p, aoff + q * 8);
            H2f[1] = read_frag(h2p, aoff + 32 + q * 8);
            f32x4 ng = {b0p, b0p, b0p, b0p};
            ng = mfma1(H2f[0], BG[0], ng);
            ng = mfma1(H2f[1], BG[1], ng);
            P1 = ng + nb;

            // fc on all waves (balanced); only wave 0 p<2 stores
            f32x4 fcC = {0.f, 0.f, 0.f, 0.f};
            fcC = mfma1(H2f[0], BF[0], fcC);
            fcC = mfma1(H2f[1], BF[1], fcC);
            if (wv == 0 && p < 2) {
#pragma unroll
                for (int r = 0; r < 4; ++r)
                    predbuf[((4 * q + r) * kTP + t) * 2 + p] = fcC[r] + fbp;
            }
        }
    }

    // flush preds: block covers out[r0*kTP*2 .. (r0+16)*kTP*2), contiguous & aligned
    __syncthreads();
    {
        float4* dst = reinterpret_cast<float4*>(out + r0 * (kTP * 2));
        const float4* src = reinterpret_cast<const float4*>(predbuf);
        for (int i = tid; i < kM * kTP * 2 / 4; i += 256)
            dst[i] = src[i];
    }
}

extern "C" void kernel_launch(void* const* d_in, const int* in_sizes, int n_in,
                              void* d_out, int out_size, void* d_ws, size_t ws_size,
                              hipStream_t stream) {
    const float* x     = (const float*)d_in[0];
    const float* eWih0 = (const float*)d_in[1];
    const float* eWhh0 = (const float*)d_in[2];
    const float* ebih0 = (const float*)d_in[3];
    const float* ebhh0 = (const float*)d_in[4];
    const float* eWih1 = (const float*)d_in[5];
    const float* eWhh1 = (const float*)d_in[6];
    const float* ebih1 = (const float*)d_in[7];
    const float* ebhh1 = (const float*)d_in[8];
    const float* dWih0 = (const float*)d_in[9];
    const float* dWhh0 = (const float*)d_in[10];
    const float* dbih0 = (const float*)d_in[11];
    const float* dbhh0 = (const float*)d_in[12];
    const float* dWih1 = (const float*)d_in[13];
    const float* dWhh1 = (const float*)d_in[14];
    const float* dbih1 = (const float*)d_in[15];
    const float* dbhh1 = (const float*)d_in[16];
    const float* fcW   = (const float*)d_in[17];
    const float* fcb   = (const float*)d_in[18];
    float* out = (float*)d_out;

    dim3 grid(kB / kM);   // 512 blocks x 4 waves; wave n owns output cols 16n..16n+15
    dim3 block(256);
    traj_rnn_kernel<<<grid, block, 0, stream>>>(
        x, eWih0, eWhh0, ebih0, ebhh0, eWih1, eWhh1, ebih1, ebhh1,
        dWih0, dWhh0, dbih0, dbhh0, dWih1, dWhh1, dbih1, dbhh1,
        fcW, fcb, out);
}

// Round 6
// 149.241 us; speedup vs baseline: 1.2061x; 1.2061x over previous
//
#include <hip/hip_runtime.h>

typedef __attribute__((ext_vector_type(8))) _Float16 f16x8;
typedef __attribute__((ext_vector_type(4))) float   f32x4;

namespace {
constexpr int kB    = 8192;
constexpr int kTH   = 11;
constexpr int kTP   = 80;
constexpr int kM    = 16;    // batch rows per group (MFMA M)
constexpr int kStrH = 72;    // H-plane row stride in fp16 units (144 B: 16B-aligned)
}

// 8 fp32 -> fp16x8 (round-to-nearest)
__device__ __forceinline__ f16x8 cvt8(const float* f) {
    f16x8 v;
#pragma unroll
    for (int j = 0; j < 8; ++j) v[j] = (_Float16)f[j];
    return v;
}

// B-fragment (single fp16) for column `col`: B[k][col] = W[col][k].
__device__ __forceinline__ void loadB1(const float* __restrict__ W, int col, int q,
                                       f16x8 (&Bf)[2]) {
#pragma unroll
    for (int c = 0; c < 2; ++c) {
        const float* src = W + col * 64 + c * 32 + q * 8;
        const float4 a = reinterpret_cast<const float4*>(src)[0];
        const float4 b = reinterpret_cast<const float4*>(src)[1];
        float f[8] = {a.x, a.y, a.z, a.w, b.x, b.y, b.z, b.w};
        Bf[c] = cvt8(f);
    }
}

// fc B-fragment: only cols p<2 are real (fcW is 2x64); others zero.
__device__ __forceinline__ void loadBfc(const float* __restrict__ fcW, int p, int q,
                                        f16x8 (&Bf)[2]) {
#pragma unroll
    for (int c = 0; c < 2; ++c) {
        float f[8];
#pragma unroll
        for (int j = 0; j < 8; ++j)
            f[j] = (p < 2) ? fcW[p * 64 + c * 32 + q * 8 + j] : 0.f;
        Bf[c] = cvt8(f);
    }
}

// G = w0 (x) fcW[0] + w1 (x) fcW[1]  (rank-2 folded feedback matrix)
__device__ __forceinline__ void loadBG(const float* __restrict__ fcW, float w0, float w1,
                                       int q, f16x8 (&Bf)[2]) {
#pragma unroll
    for (int c = 0; c < 2; ++c) {
        float f[8];
#pragma unroll
        for (int j = 0; j < 8; ++j) {
            const int k = c * 32 + q * 8 + j;
            f[j] = w0 * fcW[k] + w1 * fcW[64 + k];
        }
        Bf[c] = cvt8(f);
    }
}

__device__ __forceinline__ f16x8 read_frag(const _Float16* plane, int off) {
    return *reinterpret_cast<const f16x8*>(plane + off);
}

// single-term accumulate: D += A*B (A = fp16 h, B = fp16 W)
__device__ __forceinline__ f32x4 mfma1(f16x8 a, f16x8 b, f32x4 acc) {
    return __builtin_amdgcn_mfma_f32_16x16x32_f16(a, b, acc, 0, 0, 0);
}

// tanh via raw v_exp/v_rcp: 1 - 2*rcp(2^(2*log2e*x)+1); saturates safely.
__device__ __forceinline__ float fast_tanh(float x) {
    const float e = __builtin_amdgcn_exp2f(x * 2.8853900817779268f);  // 2/ln2
    return fmaf(-2.0f, __builtin_amdgcn_rcpf(e + 1.0f), 1.0f);
}

// R15: 256 blocks x 8 waves = TWO independent 16-row groups per block, G1's
// schedule shifted by ONE barrier slot. Every interval: G0 in phase A while
// G1 in phase B (and vice versa) -> each SIMD always hosts one A-wave + one
// B-wave; stalls of one are covered by issue of the other. Anti-phase is a
// compile-time invariant (shared barrier), immune to convoy drift.
// Per-group arithmetic is bit-identical to R9.
__global__ __attribute__((amdgpu_waves_per_eu(2, 2))) __launch_bounds__(512)
void traj_rnn_kernel(
    const float* __restrict__ x,
    const float* __restrict__ eWih0, const float* __restrict__ eWhh0,
    const float* __restrict__ ebih0, const float* __restrict__ ebhh0,
    const float* __restrict__ eWih1, const float* __restrict__ eWhh1,
    const float* __restrict__ ebih1, const float* __restrict__ ebhh1,
    const float* __restrict__ dWih0, const float* __restrict__ dWhh0,
    const float* __restrict__ dbih0, const float* __restrict__ dbhh0,
    const float* __restrict__ dWih1, const float* __restrict__ dWhh1,
    const float* __restrict__ dbih1, const float* __restrict__ dbhh1,
    const float* __restrict__ fcW, const float* __restrict__ fcb,
    float* __restrict__ out)
{
    const int tid  = threadIdx.x;
    const int grp  = tid >> 8;          // 0 or 1: independent 16-row group
    const int wvg  = (tid >> 6) & 3;    // wave-within-group: col-tile
    const int lane = tid & 63;
    const int p    = lane & 15;
    const int q    = lane >> 4;
    const int col  = wvg * 16 + p;

    __shared__ __align__(16) _Float16 H1s[2][kM * kStrH];
    __shared__ __align__(16) _Float16 H2s[2][kM * kStrH];
    __shared__ __align__(16) float xbuf[2][kM * kTH * 2];
    __shared__ __align__(16) float predbuf[2][kM * kTP * 2];

    for (int i = tid; i < 2 * kM * kTH * 2; i += 512)
        (&xbuf[0][0])[i] = x[blockIdx.x * 32 * (kTH * 2) + i];

    _Float16* h1p = H1s[grp];
    _Float16* h2p = H2s[grp];
    const float* xb = xbuf[grp];
    float*       pb = predbuf[grp];

    const f16x8 Z = {0, 0, 0, 0, 0, 0, 0, 0};
    f16x8 H1f0 = Z, H1f1 = Z, H2f0 = Z, H2f1 = Z;
    const int aoff = p * kStrH;

    // ---- load ALL weights up front (enc + dec sets live simultaneously) ----
    const float b0e = ebih0[col] + ebhh0[col];
    const float b1e = ebih1[col] + ebhh1[col];
    const float w0e = eWih0[col * 2 + 0];
    const float w1e = eWih0[col * 2 + 1];
    f16x8 B0e[2], B1e[2], B2e[2];
    loadB1(eWhh0, col, q, B0e);
    loadB1(eWih1, col, q, B1e);
    loadB1(eWhh1, col, q, B2e);

    const float b0d = dbih0[col] + dbhh0[col];
    const float b1d = dbih1[col] + dbhh1[col];
    const float w0d = dWih0[col * 2 + 0];
    const float w1d = dWih0[col * 2 + 1];
    const float fb0 = fcb[0];
    const float fb1 = fcb[1];
    const float b0p = b0d + w0d * fb0 + w1d * fb1;   // folded feedback bias
    const float fbp = (p == 0) ? fb0 : fb1;
    f16x8 B0d[2], B1d[2], B2d[2], BG[2], BF[2];
    loadB1(dWhh0, col, q, B0d);
    loadB1(dWih1, col, q, B1d);
    loadB1(dWhh1, col, q, B2d);
    loadBG(fcW, w0d, w1d, q, BG);
    loadBfc(fcW, p, q, BF);

    // carried state
    f32x4 P1 = {b0e, b0e, b0e, b0e};
    f32x4 a2 = {0.f, 0.f, 0.f, 0.f};
    f32x4 nb = {0.f, 0.f, 0.f, 0.f};

    __syncthreads();   // xbuf visible

    // ---------------- phase bodies (per-group arithmetic == R9) ----------------
    // A_enc(t): [read h2(t-1)] ; h1 = tanh(w.x_t + P1) -> write ; a2p = b1e + Whh1e.h2
    auto A_enc = [&](int t) {
        if (t > 0) {
            H2f0 = read_frag(h2p, aoff + q * 8);
            H2f1 = read_frag(h2p, aoff + 32 + q * 8);
        }
#pragma unroll
        for (int r = 0; r < 4; ++r) {
            const float2 xv = *reinterpret_cast<const float2*>(
                &xb[(4 * q + r) * (kTH * 2) + 2 * t]);
            const float h1 = fast_tanh(fmaf(w0e, xv.x, fmaf(w1e, xv.y, P1[r])));
            h1p[(4 * q + r) * kStrH + col] = (_Float16)h1;
        }
        a2 = f32x4{b1e, b1e, b1e, b1e};
        a2 = mfma1(H2f0, B2e[0], a2);
        a2 = mfma1(H2f1, B2e[1], a2);
    };
    // B_enc(t): read h1(t) ; a2 += Wih1e.h1 ; h2 -> write ; P1' = b0e + Whh0e.h1
    auto B_enc = [&](int t) {
        (void)t;
        H1f0 = read_frag(h1p, aoff + q * 8);
        H1f1 = read_frag(h1p, aoff + 32 + q * 8);
        a2 = mfma1(H1f0, B1e[0], a2);
        a2 = mfma1(H1f1, B1e[1], a2);
#pragma unroll
        for (int r = 0; r < 4; ++r) {
            const float h2 = fast_tanh(a2[r]);
            h2p[(4 * q + r) * kStrH + col] = (_Float16)h2;
        }
        f32x4 np = {b0e, b0e, b0e, b0e};
        np = mfma1(H1f0, B0e[0], np);
        np = mfma1(H1f1, B0e[1], np);
        P1 = np;
    };
    // A_dec0: read h2_enc ; P1 = b0d + Whh0d.h1_enc + w.x_last ; h1 -> write ; a2p(dec)
    auto A_dec0 = [&]() {
        H2f0 = read_frag(h2p, aoff + q * 8);
        H2f1 = read_frag(h2p, aoff + 32 + q * 8);
        P1 = f32x4{b0d, b0d, b0d, b0d};
        P1 = mfma1(H1f0, B0d[0], P1);    // H1f = h1_enc[10], live from B_enc(10)
        P1 = mfma1(H1f1, B0d[1], P1);
#pragma unroll
        for (int r = 0; r < 4; ++r) {
            const float2 xv = *reinterpret_cast<const float2*>(
                &xb[(4 * q + r) * (kTH * 2) + 2 * (kTH - 1)]);
            P1[r] = fmaf(w0d, xv.x, fmaf(w1d, xv.y, P1[r]));
        }
#pragma unroll
        for (int r = 0; r < 4; ++r)
            h1p[(4 * q + r) * kStrH + col] = (_Float16)fast_tanh(P1[r]);
        a2 = f32x4{b1d, b1d, b1d, b1d};
        a2 = mfma1(H2f0, B2d[0], a2);
        a2 = mfma1(H2f1, B2d[1], a2);
    };
    // A_dec(t>=1): read h2(t-1) ; ng = b0p + G.h2 ; P1 = ng+nb ; fc->pred[t-1] ;
    //              h1 = tanh(P1) -> write ; a2p = b1d + Whh1d.h2
    auto A_dec = [&](int t) {
        H2f0 = read_frag(h2p, aoff + q * 8);
        H2f1 = read_frag(h2p, aoff + 32 + q * 8);
        f32x4 ng = {b0p, b0p, b0p, b0p};
        ng = mfma1(H2f0, BG[0], ng);
        ng = mfma1(H2f1, BG[1], ng);
        P1 = ng + nb;
        f32x4 fcC = {0.f, 0.f, 0.f, 0.f};
        fcC = mfma1(H2f0, BF[0], fcC);
        fcC = mfma1(H2f1, BF[1], fcC);
        if (wvg == 0 && p < 2) {
#pragma unroll
            for (int r = 0; r < 4; ++r)
                pb[((4 * q + r) * kTP + (t - 1)) * 2 + p] = fcC[r] + fbp;
        }
#pragma unroll
        for (int r = 0; r < 4; ++r)
            h1p[(4 * q + r) * kStrH + col] = (_Float16)fast_tanh(P1[r]);
        a2 = f32x4{b1d, b1d, b1d, b1d};
        a2 = mfma1(H2f0, B2d[0], a2);
        a2 = mfma1(H2f1, B2d[1], a2);
    };
    // B_dec(t): read h1(t) ; a2 += Wih1d.h1 ; h2 -> write ; nb = Whh0d.h1
    auto B_dec = [&](int t) {
        (void)t;
        H1f0 = read_frag(h1p, aoff + q * 8);
        H1f1 = read_frag(h1p, aoff + 32 + q * 8);
        a2 = mfma1(H1f0, B1d[0], a2);
        a2 = mfma1(H1f1, B1d[1], a2);
#pragma unroll
        for (int r = 0; r < 4; ++r) {
            const float h2 = fast_tanh(a2[r]);
            h2p[(4 * q + r) * kStrH + col] = (_Float16)h2;
        }
        nb = f32x4{0.f, 0.f, 0.f, 0.f};
        nb = mfma1(H1f0, B0d[0], nb);
        nb = mfma1(H1f1, B0d[1], nb);
    };
    // FC_ep: read h2(79) ; fc -> pred[79]
    auto FC_ep = [&]() {
        H2f0 = read_frag(h2p, aoff + q * 8);
        H2f1 = read_frag(h2p, aoff + 32 + q * 8);
        f32x4 fcC = {0.f, 0.f, 0.f, 0.f};
        fcC = mfma1(H2f0, BF[0], fcC);
        fcC = mfma1(H2f1, BF[1], fcC);
        if (wvg == 0 && p < 2) {
#pragma unroll
            for (int r = 0; r < 4; ++r)
                pb[((4 * q + r) * kTP + (kTP - 1)) * 2 + p] = fcC[r] + fbp;
        }
    };

    // ---------------- staggered slot schedule ----------------
    // slot 0: G0 A_e(0) | G1 idle
    if (grp == 0) A_enc(0);
    __syncthreads();
    // encoder: slots 1..21
#pragma unroll 1
    for (int k = 0; ; ++k) {
        if (grp == 0) B_enc(k); else A_enc(k);     // odd slot 2k+1
        __syncthreads();
        if (k == kTH - 1) break;
        if (grp == 0) A_enc(k + 1); else B_enc(k); // even slot 2k+2
        __syncthreads();
    }
    // slot 22: G0 A_d(0) | G1 B_e(10)
    if (grp == 0) A_dec0(); else B_enc(kTH - 1);
    __syncthreads();
    // slot 23: G0 B_d(0) | G1 A_d(0)
    if (grp == 0) B_dec(0); else A_dec0();
    __syncthreads();
    // decoder main: slots 24..181
#pragma unroll 1
    for (int k = 0; k < kTP - 1; ++k) {
        if (grp == 0) A_dec(k + 1); else B_dec(k);
        __syncthreads();
        if (grp == 0) B_dec(k + 1); else A_dec(k + 1);
        __syncthreads();
    }
    // slot 182: G0 fc-epilogue | G1 B_d(79)
    if (grp == 0) FC_ep(); else B_dec(kTP - 1);
    __syncthreads();
    // slot 183: G1 fc-epilogue
    if (grp != 0) FC_ep();
    __syncthreads();

    // flush both groups' preds: block covers out rows blockIdx*32 .. +32
    {
        float4* dst = reinterpret_cast<float4*>(out + blockIdx.x * 32 * (kTP * 2));
        const float4* src = reinterpret_cast<const float4*>(&predbuf[0][0]);
        for (int i = tid; i < 2 * kM * kTP * 2 / 4; i += 512)
            dst[i] = src[i];
    }
}

extern "C" void kernel_launch(void* const* d_in, const int* in_sizes, int n_in,
                              void* d_out, int out_size, void* d_ws, size_t ws_size,
                              hipStream_t stream) {
    const float* x     = (const float*)d_in[0];
    const float* eWih0 = (const float*)d_in[1];
    const float* eWhh0 = (const float*)d_in[2];
    const float* ebih0 = (const float*)d_in[3];
    const float* ebhh0 = (const float*)d_in[4];
    const float* eWih1 = (const float*)d_in[5];
    const float* eWhh1 = (const float*)d_in[6];
    const float* ebih1 = (const float*)d_in[7];
    const float* ebhh1 = (const float*)d_in[8];
    const float* dWih0 = (const float*)d_in[9];
    const float* dWhh0 = (const float*)d_in[10];
    const float* dbih0 = (const float*)d_in[11];
    const float* dbhh0 = (const float*)d_in[12];
    const float* dWih1 = (const float*)d_in[13];
    const float* dWhh1 = (const float*)d_in[14];
    const float* dbih1 = (const float*)d_in[15];
    const float* dbhh1 = (const float*)d_in[16];
    const float* fcW   = (const float*)d_in[17];
    const float* fcb   = (const float*)d_in[18];
    float* out = (float*)d_out;

    dim3 grid(kB / 32);   // 256 blocks x 8 waves (two phase-offset 16-row groups)
    dim3 block(512);
    traj_rnn_kernel<<<grid, block, 0, stream>>>(
        x, eWih0, eWhh0, ebih0, ebhh0, eWih1, eWhh1, ebih1, ebhh1,
        dWih0, dWhh0, dbih0, dbhh0, dWih1, dWhh1, dbih1, dbhh1,
        fcW, fcb, out);
}